// Round 6
// baseline (155.299 us; speedup 1.0000x reference)
//
#include <hip/hip_runtime.h>
#include <hip/hip_fp16.h>

// DSA varlen sparse attention, MI355X — round 6.
// R5 post-mortem: VGPR stayed 36 -> compiler sank the V register-prefetch
// AGAIN (register-pressure heuristic). Still ~30us of serialized latency
// over the ~27us fp16 transaction floor.
// Fixes the compiler cannot undo:
//   1) V-prefetch via global_load_lds (async DMA, NO register destination,
//      nothing to sink). Issued before phase 1; vmcnt retires in-order so
//      K-waits imply V landed. 8KB LDS/wave.
//   2) Unnormalized accumulation: acc += (e_k*sc_k) * v_k needs only the
//      per-row score; wave-wide S2 reduce moves OFF the critical path and
//      overlaps the PV fma stream. Normalize acc/S2 once at the end.
// Error budget: unnormalized fp16 accum ~4e-3 rel -> absmax ~0.03 << 0.083.

#define T_TOK 4096
#define NH    16
#define HD    64
#define KSEL  64
#define KV_ELEMS (T_TOK * NH * HD)     // 4194304 per tensor

typedef _Float16 h2v __attribute__((ext_vector_type(2)));

static __device__ __forceinline__ h2v u2h2v(unsigned u) {
    return __builtin_bit_cast(h2v, u);
}
static __device__ __forceinline__ __half2 u2h2(unsigned u) {
    return __builtin_bit_cast(__half2, u);
}
static __device__ __forceinline__ unsigned h22u(__half2 h) {
    return __builtin_bit_cast(unsigned, h);
}
static __device__ __forceinline__ h2v f2h2v(float a, float b) {
    __half2 t = __floats2half2_rn(a, b);   // v_cvt_pkrtz_f16_f32
    return __builtin_bit_cast(h2v, t);
}

// ---------------- fp32 -> fp16 conversion pre-pass ----------------
__global__ __launch_bounds__(256) void cvt_fp16(
    const float4* __restrict__ kM, const float4* __restrict__ vM,
    uint2* __restrict__ kH, uint2* __restrict__ vH)
{
    const int n4 = KV_ELEMS / 4;
    const int i  = blockIdx.x * blockDim.x + threadIdx.x;
    const bool isK = i < n4;
    const float4 f = isK ? kM[i] : vM[i - n4];
    __half2 lo = __floats2half2_rn(f.x, f.y);
    __half2 hi = __floats2half2_rn(f.z, f.w);
    uint2 u;
    u.x = h22u(lo);
    u.y = h22u(hi);
    if (isK) kH[i] = u; else vH[i - n4] = u;
}

// ---------------- main kernel ----------------
__global__ __launch_bounds__(256) void dsa_sparse_attn(
    const float*  __restrict__ qM,
    const __half* __restrict__ kH,
    const __half* __restrict__ vH,
    const int*    __restrict__ cu,
    const int*    __restrict__ tidx,
    const float*  __restrict__ tsc,
    float*        __restrict__ out,
    int num_docs)
{
    // Per-wave V staging: 8 DMA instrs x 64 lanes x 16B = 8KB per wave.
    __shared__ uint4 sV[4][512];   // 32 KB/block -> 5 blocks/CU

    const int wave = threadIdx.x >> 6;
    const int lane = threadIdx.x & 63;

    // XCD-aware (doc,head)-slice swizzle (kept from R4).
    const int b            = blockIdx.x;
    const int xcd          = b & 7;
    const int j            = b >> 3;
    const int token_block  = j & 255;
    const int slice_within = j >> 8;
    const int s            = xcd + (slice_within << 3);
    const int h            = s & (NH - 1);
    const int t            = (s >> 4) * (T_TOK / 4) + token_block * 4 + wave;
    const int gid          = t * NH + h;

    // --- doc segment (wave-uniform) ---
    int seg = 0;
    for (int i = 1; i < num_docs; ++i)
        if (t >= cu[i]) seg = i;
    const int start = cu[seg];
    const int len   = cu[seg + 1] - start;

    // --- per-lane gather index (k = lane), clamped ---
    int idx = tidx[t * KSEL + lane];
    int loc = idx - start;
    loc = loc < 0 ? 0 : loc;
    loc = loc > len - 1 ? len - 1 : loc;
    const int g = start + loc;                 // K/V row for k = lane
    const float sc = tsc[t * KSEL + lane];

    const int laneCol = lane & 3;   // P1: uint4 (16B) sub-chunk
    const int laneRow = lane >> 2;  // P1: row within group of 16
    const int laneQ8  = lane >> 3;  // P3: row slot (8 rows/instr)
    const int laneC8  = lane & 7;   // P3: uint4 column (full 128B row)

    const uint4* kf = (const uint4*)kH;   // fp16 row = 8 uint4 (128B)
    const int hc1 = h * 8 + laneCol;

    // ===== V prefetch: async DMA to LDS, issued FIRST (no reg dest, =====
    // ===== cannot be sunk; latency hides under the whole QK phase)  =====
    {
        const __half* vbase = vH;
        #pragma unroll
        for (int i = 0; i < 8; ++i) {
            const int gr = __shfl(g, i * 8 + laneQ8, 64);
            const __half* gp = vbase + ((gr * NH + h) << 6) + (laneC8 << 3);
            __builtin_amdgcn_global_load_lds(
                (const __attribute__((address_space(1))) unsigned int*)gp,
                (__attribute__((address_space(3))) unsigned int*)&sV[wave][i * 64],
                16, 0, 0);
        }
    }

    // --- q -> fp16 chunks for this lane's K sub-segment ---
    const float4* qv = (const float4*)(qM + gid * HD);
    const float4 f0 = qv[laneCol * 2];
    const float4 f1 = qv[laneCol * 2 + 1];
    const float4 f2 = qv[8 + laneCol * 2];
    const float4 f3 = qv[8 + laneCol * 2 + 1];
    h2v qa[4] = { f2h2v(f0.x, f0.y), f2h2v(f0.z, f0.w),
                  f2h2v(f1.x, f1.y), f2h2v(f1.z, f1.w) };
    h2v qb[4] = { f2h2v(f2.x, f2.y), f2h2v(f2.z, f2.w),
                  f2h2v(f3.x, f3.y), f2h2v(f3.z, f3.w) };

    // ================= Phase 1: scores (QK^T), fdot2 =================
    float score = 0.f;
    #pragma unroll
    for (int rg = 0; rg < 4; ++rg) {
        const int grow = __shfl(g, rg * 16 + laneRow, 64);
        const uint4 kA = kf[grow * 128 + hc1];        // dims [8c, 8c+8)
        const uint4 kB = kf[grow * 128 + hc1 + 4];    // dims [32+8c, +8)
        float p = 0.f;
        p = __builtin_amdgcn_fdot2(u2h2v(kA.x), qa[0], p, false);
        p = __builtin_amdgcn_fdot2(u2h2v(kA.y), qa[1], p, false);
        p = __builtin_amdgcn_fdot2(u2h2v(kA.z), qa[2], p, false);
        p = __builtin_amdgcn_fdot2(u2h2v(kA.w), qa[3], p, false);
        p = __builtin_amdgcn_fdot2(u2h2v(kB.x), qb[0], p, false);
        p = __builtin_amdgcn_fdot2(u2h2v(kB.y), qb[1], p, false);
        p = __builtin_amdgcn_fdot2(u2h2v(kB.z), qb[2], p, false);
        p = __builtin_amdgcn_fdot2(u2h2v(kB.w), qb[3], p, false);
        p += __shfl_xor(p, 1, 64);
        p += __shfl_xor(p, 2, 64);
        const float got = __shfl(p, (lane & 15) << 2, 64);
        if (rg == (lane >> 4)) score = got;
    }
    score *= 0.125f;   // D^-0.5

    // ===== Phase 2a: UNNORMALIZED weight p = e*sc (per-lane only — no
    // wave-wide reduce on the critical path; |score|<~6 so exp is safe) =====
    const float e = __expf(score);
    const float p = e * sc;
    // replicated half2 so one shfl delivers a pk_fma operand (p <= ~150, fp16-safe)
    const unsigned hb  = (unsigned)__builtin_bit_cast(unsigned short, __float2half(p));
    const unsigned ppk = hb | (hb << 16);

    // ================= Phase 3: PV from LDS, packed fp16 fma =================
    asm volatile("s_waitcnt vmcnt(0)" ::: "memory");   // V DMA landed long ago
    __half2 acc[4];
    acc[0] = u2h2(0u); acc[1] = u2h2(0u); acc[2] = u2h2(0u); acc[3] = u2h2(0u);
    #pragma unroll
    for (int i = 0; i < 8; ++i) {
        const unsigned pu = (unsigned)__shfl((int)ppk, i * 8 + laneQ8, 64);
        const __half2 pk2 = u2h2(pu);
        const uint4 vv = sV[wave][i * 64 + lane];      // ds_read_b128
        acc[0] = __hfma2(pk2, u2h2(vv.x), acc[0]);
        acc[1] = __hfma2(pk2, u2h2(vv.y), acc[1]);
        acc[2] = __hfma2(pk2, u2h2(vv.z), acc[2]);
        acc[3] = __hfma2(pk2, u2h2(vv.w), acc[3]);
    }

    // ===== Phase 2b: S2 = sum(p) — off the critical path, overlaps P3 =====
    float S2 = p;
    #pragma unroll
    for (int off = 32; off; off >>= 1)
        S2 += __shfl_xor(S2, off, 64);

    // reduce acc across the 8 row-groups
    #pragma unroll
    for (int off = 8; off <= 32; off <<= 1) {
        #pragma unroll
        for (int jj = 0; jj < 4; ++jj) {
            const unsigned o = (unsigned)__shfl_xor((int)h22u(acc[jj]), off, 64);
            acc[jj] = __hadd2(acc[jj], u2h2(o));
        }
    }

    if (laneQ8 == 0) {
        const float inv = __builtin_amdgcn_rcpf(S2);
        const float2 a0 = __half22float2(acc[0]);
        const float2 a1 = __half22float2(acc[1]);
        const float2 a2 = __half22float2(acc[2]);
        const float2 a3 = __half22float2(acc[3]);
        float4* op = (float4*)(out + gid * HD + laneC8 * 8);
        op[0] = make_float4(a0.x * inv, a0.y * inv, a1.x * inv, a1.y * inv);
        op[1] = make_float4(a2.x * inv, a2.y * inv, a3.x * inv, a3.y * inv);
    }
}

extern "C" void kernel_launch(void* const* d_in, const int* in_sizes, int n_in,
                              void* d_out, int out_size, void* d_ws, size_t ws_size,
                              hipStream_t stream) {
    const float* q   = (const float*)d_in[0];
    const float* k   = (const float*)d_in[1];
    const float* v   = (const float*)d_in[2];
    const int*   cu  = (const int*)d_in[3];
    const int*   ti  = (const int*)d_in[4];
    const float* ts  = (const float*)d_in[5];
    float*       out = (float*)d_out;
    const int num_docs = in_sizes[3] - 1;

    __half* kH = (__half*)d_ws;
    __half* vH = kH + KV_ELEMS;

    const int n4 = KV_ELEMS / 4;
    hipLaunchKernelGGL(cvt_fp16, dim3(2 * n4 / 256), dim3(256), 0, stream,
                       (const float4*)k, (const float4*)v,
                       (uint2*)kH, (uint2*)vH);

    const int total_waves = T_TOK * NH;          // 65536 -> 16384 blocks
    hipLaunchKernelGGL(dsa_sparse_attn, dim3(total_waves / 4), dim3(256), 0,
                       stream, q, (const __half*)kH, (const __half*)vH,
                       cu, ti, ts, out, num_docs);
}

// Round 7
// 144.258 us; speedup vs baseline: 1.0765x; 1.0765x over previous
//
#include <hip/hip_runtime.h>
#include <hip/hip_fp16.h>

// DSA varlen sparse attention, MI355X — round 7.
// R6 post-mortem: LDS DMA staging cost occupancy (62->37%) -> regression; reverted.
// R5 re-model: THREE ~27us pipes — VMEM lines (~27), VALU (~26), and the
// overlooked LDS/shfl pipe (~46 bpermute/swizzle per lane ~ 29us). Fix is
// structural: P1 layout == P3 layout (8 lanes/row, laneQ8=row slot), so the
// lane computing row r's score IS the lane needing row r's weight — zero
// score routing, zero weight broadcast. Within-row dot reduce via DPP adds
// (quad_perm xor1/xor2 + row_half_mirror as xor4) = pure VALU, no LDS pipe.
// One g-bpermute per row-group serves both K and V. Unnormalized fp16
// accumulate (R6-proven numerics), S2 reduced off the critical path.
// LDS-pipe ops 46 -> ~23. Predict main kernel ~38-44us.

#define T_TOK 4096
#define NH    16
#define HD    64
#define KSEL  64
#define KV_ELEMS (T_TOK * NH * HD)     // 4194304 per tensor

typedef _Float16 h2v __attribute__((ext_vector_type(2)));

static __device__ __forceinline__ h2v u2h2v(unsigned u) {
    return __builtin_bit_cast(h2v, u);
}
static __device__ __forceinline__ __half2 u2h2(unsigned u) {
    return __builtin_bit_cast(__half2, u);
}
static __device__ __forceinline__ h2v f2h2v(float a, float b) {
    __half2 t = __floats2half2_rn(a, b);   // v_cvt_pkrtz_f16_f32
    return __builtin_bit_cast(h2v, t);
}

// Cross-lane add via DPP — VALU pipe only, no LDS traffic.
// 0xB1 = quad_perm[1,0,3,2] (xor1)   0x4E = quad_perm[2,3,0,1] (xor2)
// 0x141 = row_half_mirror (acts as xor4 on quad-uniform values)
// 0x140 = row_mirror      (acts as xor8 on 8-group-uniform values)
template<int CTRL>
static __device__ __forceinline__ float dpp_addf(float x) {
    const int s = __builtin_amdgcn_update_dpp(
        0, __builtin_bit_cast(int, x), CTRL, 0xF, 0xF, true);
    return x + __builtin_bit_cast(float, s);
}

// Cross-lane add via ds_swizzle (xor within 32-lane halves).
template<int IMM>
static __device__ __forceinline__ float swz_addf(float x) {
    const int s = __builtin_amdgcn_ds_swizzle(__builtin_bit_cast(int, x), IMM);
    return x + __builtin_bit_cast(float, s);
}
template<int IMM>
static __device__ __forceinline__ __half2 swz_hadd2(__half2 x) {
    const int s = __builtin_amdgcn_ds_swizzle(__builtin_bit_cast(int, x), IMM);
    return __hadd2(x, __builtin_bit_cast(__half2, s));
}
static __device__ __forceinline__ __half2 sh32_hadd2(__half2 x) {
    const int s = __shfl_xor(__builtin_bit_cast(int, x), 32, 64);
    return __hadd2(x, __builtin_bit_cast(__half2, s));
}

// ---------------- fp32 -> fp16 conversion pre-pass ----------------
__global__ __launch_bounds__(256) void cvt_fp16(
    const float4* __restrict__ kM, const float4* __restrict__ vM,
    uint2* __restrict__ kH, uint2* __restrict__ vH)
{
    const int n4 = KV_ELEMS / 4;
    const int i  = blockIdx.x * blockDim.x + threadIdx.x;
    const bool isK = i < n4;
    const float4 f = isK ? kM[i] : vM[i - n4];
    __half2 lo = __floats2half2_rn(f.x, f.y);
    __half2 hi = __floats2half2_rn(f.z, f.w);
    uint2 u;
    u.x = __builtin_bit_cast(unsigned, lo);
    u.y = __builtin_bit_cast(unsigned, hi);
    if (isK) kH[i] = u; else vH[i - n4] = u;
}

// ---------------- main kernel ----------------
__global__ __launch_bounds__(256) void dsa_sparse_attn(
    const float*  __restrict__ qM,
    const __half* __restrict__ kH,
    const __half* __restrict__ vH,
    const int*    __restrict__ cu,
    const int*    __restrict__ tidx,
    const float*  __restrict__ tsc,
    float*        __restrict__ out,
    int num_docs)
{
    const int wave = threadIdx.x >> 6;
    const int lane = threadIdx.x & 63;

    // XCD-aware (doc,head)-slice swizzle (kept from R4).
    const int b            = blockIdx.x;
    const int xcd          = b & 7;
    const int j            = b >> 3;
    const int token_block  = j & 255;
    const int slice_within = j >> 8;
    const int s            = xcd + (slice_within << 3);
    const int h            = s & (NH - 1);
    const int t            = (s >> 4) * (T_TOK / 4) + token_block * 4 + wave;
    const int gid          = t * NH + h;

    // --- doc segment (wave-uniform) ---
    int seg = 0;
    for (int i = 1; i < num_docs; ++i)
        if (t >= cu[i]) seg = i;
    const int start = cu[seg];
    const int len   = cu[seg + 1] - start;

    // --- per-lane gather index (k = lane), clamped ---
    int idx = tidx[t * KSEL + lane];
    int loc = idx - start;
    loc = loc < 0 ? 0 : loc;
    loc = loc > len - 1 ? len - 1 : loc;
    const int g = start + loc;                 // K/V row for k = lane

    const int laneQ8 = lane >> 3;   // row slot within each group of 8 rows
    const int laneC8 = lane & 7;    // uint4 (16B) chunk within the 128B row

    // --- q -> fp16 chunk for this lane's column slice (dims [laneC8*8,+8)) ---
    const float4* qv = (const float4*)(qM + gid * HD);
    const float4 fA = qv[laneC8 * 2];
    const float4 fB = qv[laneC8 * 2 + 1];
    const h2v q0 = f2h2v(fA.x, fA.y);
    const h2v q1 = f2h2v(fA.z, fA.w);
    const h2v q2 = f2h2v(fB.x, fB.y);
    const h2v q3 = f2h2v(fB.z, fB.w);

    const uint4* kf = (const uint4*)kH;   // fp16 row = 8 uint4 (128B)
    const uint4* vf = (const uint4*)vH;
    const float* scb = tsc + t * KSEL;

    float S2part = 0.f;
    __half2 acc0 = u2h2(0u), acc1 = u2h2(0u), acc2 = u2h2(0u), acc3 = u2h2(0u);

    #pragma unroll
    for (int rg = 0; rg < 8; ++rg) {
        const int row = rg * 8 + laneQ8;          // this lane's row this step
        const int gr  = __shfl(g, row, 64);       // 1 bpermute serves K and V
        const int base = (gr * NH + h) * 8 + laneC8;
        const uint4 kk = kf[base];                // 8 rows x 128B -> 16 lines
        const uint4 vv = vf[base];
        const float sck = scb[row];               // 8 addrs, 1 line

        // partial dot over this lane's 8 dims, fp32 accumulate
        float p = 0.f;
        p = __builtin_amdgcn_fdot2(u2h2v(kk.x), q0, p, false);
        p = __builtin_amdgcn_fdot2(u2h2v(kk.y), q1, p, false);
        p = __builtin_amdgcn_fdot2(u2h2v(kk.z), q2, p, false);
        p = __builtin_amdgcn_fdot2(u2h2v(kk.w), q3, p, false);
        // full row dot on all 8 lanes of this row-slot — pure DPP, no LDS
        p = dpp_addf<0xB1>(p);     // xor1
        p = dpp_addf<0x4E>(p);     // xor2
        p = dpp_addf<0x141>(p);    // xor4 (quad-uniform -> half_mirror ok)

        // unnormalized weight; score*0.125 = D^-0.5; |score|<~6 so exp safe
        const float w = __expf(p * 0.125f) * sck;
        S2part += w;
        const __half2 w2 = __floats2half2_rn(w, w);   // replicated half2
        acc0 = __hfma2(w2, u2h2(vv.x), acc0);
        acc1 = __hfma2(w2, u2h2(vv.y), acc1);
        acc2 = __hfma2(w2, u2h2(vv.z), acc2);
        acc3 = __hfma2(w2, u2h2(vv.w), acc3);
    }

    // ---- S2 = sum of all 64 weights (S2part uniform within 8-groups) ----
    float S2 = S2part;
    S2 = dpp_addf<0x140>(S2);      // xor8 via row_mirror (8-group-uniform)
    S2 = swz_addf<0x401F>(S2);     // xor16
    S2 += __shfl_xor(S2, 32, 64);  // xor32

    // ---- reduce acc across the 8 row-slots (lane bits 3..5) ----
    acc0 = swz_hadd2<0x201F>(acc0); acc1 = swz_hadd2<0x201F>(acc1);
    acc2 = swz_hadd2<0x201F>(acc2); acc3 = swz_hadd2<0x201F>(acc3);
    acc0 = swz_hadd2<0x401F>(acc0); acc1 = swz_hadd2<0x401F>(acc1);
    acc2 = swz_hadd2<0x401F>(acc2); acc3 = swz_hadd2<0x401F>(acc3);
    acc0 = sh32_hadd2(acc0); acc1 = sh32_hadd2(acc1);
    acc2 = sh32_hadd2(acc2); acc3 = sh32_hadd2(acc3);

    if (laneQ8 == 0) {
        const float inv = __builtin_amdgcn_rcpf(S2);
        const float2 a0 = __half22float2(acc0);
        const float2 a1 = __half22float2(acc1);
        const float2 a2 = __half22float2(acc2);
        const float2 a3 = __half22float2(acc3);
        float4* op = (float4*)(out + gid * HD + laneC8 * 8);
        op[0] = make_float4(a0.x * inv, a0.y * inv, a1.x * inv, a1.y * inv);
        op[1] = make_float4(a2.x * inv, a2.y * inv, a3.x * inv, a3.y * inv);
    }
}

extern "C" void kernel_launch(void* const* d_in, const int* in_sizes, int n_in,
                              void* d_out, int out_size, void* d_ws, size_t ws_size,
                              hipStream_t stream) {
    const float* q   = (const float*)d_in[0];
    const float* k   = (const float*)d_in[1];
    const float* v   = (const float*)d_in[2];
    const int*   cu  = (const int*)d_in[3];
    const int*   ti  = (const int*)d_in[4];
    const float* ts  = (const float*)d_in[5];
    float*       out = (float*)d_out;
    const int num_docs = in_sizes[3] - 1;

    __half* kH = (__half*)d_ws;
    __half* vH = kH + KV_ELEMS;

    const int n4 = KV_ELEMS / 4;
    hipLaunchKernelGGL(cvt_fp16, dim3(2 * n4 / 256), dim3(256), 0, stream,
                       (const float4*)k, (const float4*)v,
                       (uint2*)kH, (uint2*)vH);

    const int total_waves = T_TOK * NH;          // 65536 -> 16384 blocks
    hipLaunchKernelGGL(dsa_sparse_attn, dim3(total_waves / 4), dim3(256), 0,
                       stream, q, (const __half*)kH, (const __half*)vH,
                       cu, ti, ts, out, num_docs);
}